// Round 13
// baseline (138.473 us; speedup 1.0000x reference)
//
#include <hip/hip_runtime.h>
#include <hip/hip_bf16.h>

typedef __bf16 bf16x8 __attribute__((ext_vector_type(8)));
typedef float f32x4 __attribute__((ext_vector_type(4)));
typedef float f32x16 __attribute__((ext_vector_type(16)));
typedef int i32x4 __attribute__((ext_vector_type(4)));
typedef int i32x8 __attribute__((ext_vector_type(8)));
typedef unsigned int u32;

#define MFMA16 __builtin_amdgcn_mfma_f32_16x16x32_bf16
// MX-scaled fp8 MFMA, K=64, unity scales (E8M0 byte 0x7F = 2^0)
#define MFMASC(a, b, c) \
  __builtin_amdgcn_mfma_scale_f32_32x32x64_f8f6f4((a), (b), (c), 0, 0, 0, 0x7F7F7F7F, 0, 0x7F7F7F7F)

#define LOG2E 1.44269504f

__device__ __forceinline__ unsigned short f2b(float f) {
  return __builtin_bit_cast(unsigned short, (__bf16)f);
}

__device__ __forceinline__ u32 pk4(float a, float b, float c, float d) {
  int v = __builtin_amdgcn_cvt_pk_fp8_f32(a, b, 0, false);
  v = __builtin_amdgcn_cvt_pk_fp8_f32(c, d, v, true);
  return (u32)v;
}

__device__ __forceinline__ void gload_lds16(const void* g, void* l) {
  __builtin_amdgcn_global_load_lds(
      (const __attribute__((address_space(1))) unsigned int*)g,
      (__attribute__((address_space(3))) unsigned int*)l, 16, 0, 0);
}

// ---------------------------------------------------------------------------
// Kernel 0: W (fp32) -> bf16
// ---------------------------------------------------------------------------
__global__ __launch_bounds__(256) void k_wconv(const float* __restrict__ Wa,
                                               const float* __restrict__ Wb,
                                               const float* __restrict__ Wm,
                                               unsigned short* __restrict__ W16) {
  const int m = blockIdx.y;
  const float* W = (m == 0) ? Wa : (m == 1) ? Wb : Wm;
  const int i = (blockIdx.x * 256 + threadIdx.x) * 8;
  float4 a = *reinterpret_cast<const float4*>(W + i);
  float4 b = *reinterpret_cast<const float4*>(W + i + 4);
  ushort4 lo, hi;
  lo.x = f2b(a.x); lo.y = f2b(a.y); lo.z = f2b(a.z); lo.w = f2b(a.w);
  hi.x = f2b(b.x); hi.y = f2b(b.y); hi.z = f2b(b.z); hi.w = f2b(b.w);
  unsigned short* dst = W16 + m * 65536 + i;
  *reinterpret_cast<ushort4*>(dst) = lo;
  *reinterpret_cast<ushort4*>(dst + 4) = hi;
}

// ---------------------------------------------------------------------------
// Kernel 1: fused transpose + 3 projections. 32 n-rows/block, grid (128,4).
// ---------------------------------------------------------------------------
__global__ __launch_bounds__(256) void k_proj(
    const float* __restrict__ x, const unsigned short* __restrict__ W16,
    const float* __restrict__ ba, const float* __restrict__ bb,
    const float* __restrict__ bm, const float* __restrict__ gamma,
    const float* __restrict__ beta, const float* __restrict__ rmean,
    const float* __restrict__ rvar,
    unsigned char* __restrict__ Q8, unsigned char* __restrict__ K8,
    unsigned char* __restrict__ V8) {
  __shared__ float tile[256][36];
  __shared__ __align__(16) unsigned short XT_lds[32 * 256];
  const int nt = blockIdx.x, b = blockIdx.y;
  const int n0 = nt * 32;
  const int tid = threadIdx.x, w = tid >> 6, l = tid & 63;
  const int li = l & 15, lk = l >> 4;
  {
    const int cr = tid >> 3, j4 = (tid & 7) * 4;
#pragma unroll
    for (int p = 0; p < 8; ++p) {
      int c = p * 32 + cr;
      float4 v = *reinterpret_cast<const float4*>(
          x + ((size_t)(b * 256 + c)) * 4096 + n0 + j4);
      *reinterpret_cast<float4*>(&tile[c][j4]) = v;
    }
  }
  __syncthreads();
  {
    const int n = tid & 31, cb8 = (tid >> 5) * 32;
#pragma unroll
    for (int p = 0; p < 8; ++p) {
      int c0 = cb8 + p * 4;
      ushort4 o;
      o.x = f2b(tile[c0][n]); o.y = f2b(tile[c0 + 1][n]);
      o.z = f2b(tile[c0 + 2][n]); o.w = f2b(tile[c0 + 3][n]);
      unsigned off = ((unsigned)(n * 512 + c0 * 2)) ^ (unsigned)((n & 7) << 4);
      *reinterpret_cast<ushort4*>((char*)XT_lds + off) = o;
    }
  }
  __syncthreads();
  bf16x8 af[2][8];
#pragma unroll
  for (int rs = 0; rs < 2; ++rs) {
    const int row = rs * 16 + li;
#pragma unroll
    for (int kk = 0; kk < 8; ++kk) {
      unsigned off = ((unsigned)(row * 512 + kk * 64 + lk * 16)) ^ (unsigned)((row & 7) << 4);
      af[rs][kk] = *reinterpret_cast<const bf16x8*>((const char*)XT_lds + off);
    }
  }
  const int ofb = w * 4;
  f32x4 zero = {0.f, 0.f, 0.f, 0.f};
  f32x4 acc[2][4];
  // ---- mode 0: Q (swapped), *log2e ----
  {
#pragma unroll
    for (int rs = 0; rs < 2; ++rs)
#pragma unroll
      for (int i = 0; i < 4; ++i) acc[rs][i] = zero;
#pragma unroll
    for (int kk = 0; kk < 8; ++kk)
#pragma unroll
      for (int of = 0; of < 4; ++of) {
        bf16x8 bfv = *reinterpret_cast<const bf16x8*>(
            W16 + (size_t)((ofb + of) * 16 + li) * 256 + kk * 32 + lk * 8);
        acc[0][of] = MFMA16(bfv, af[0][kk], acc[0][of], 0, 0, 0);
        acc[1][of] = MFMA16(bfv, af[1][kk], acc[1][of], 0, 0, 0);
      }
#pragma unroll
    for (int rs = 0; rs < 2; ++rs) {
      const int n = n0 + rs * 16 + li;
      unsigned char* out = Q8 + ((size_t)b * 4096 + n) * 256;
#pragma unroll
      for (int of = 0; of < 4; ++of) {
        int c0 = (ofb + of) * 16 + lk * 4;
        float4 bs = *reinterpret_cast<const float4*>(ba + c0);
        u32 v = pk4((acc[rs][of][0] + bs.x) * LOG2E, (acc[rs][of][1] + bs.y) * LOG2E,
                    (acc[rs][of][2] + bs.z) * LOG2E, (acc[rs][of][3] + bs.w) * LOG2E);
        *reinterpret_cast<u32*>(out + c0) = v;
      }
    }
  }
  // ---- mode 1: K (swapped) ----
  {
#pragma unroll
    for (int rs = 0; rs < 2; ++rs)
#pragma unroll
      for (int i = 0; i < 4; ++i) acc[rs][i] = zero;
#pragma unroll
    for (int kk = 0; kk < 8; ++kk)
#pragma unroll
      for (int of = 0; of < 4; ++of) {
        bf16x8 bfv = *reinterpret_cast<const bf16x8*>(
            W16 + 65536 + (size_t)((ofb + of) * 16 + li) * 256 + kk * 32 + lk * 8);
        acc[0][of] = MFMA16(bfv, af[0][kk], acc[0][of], 0, 0, 0);
        acc[1][of] = MFMA16(bfv, af[1][kk], acc[1][of], 0, 0, 0);
      }
#pragma unroll
    for (int rs = 0; rs < 2; ++rs) {
      const int n = n0 + rs * 16 + li;
      unsigned char* out = K8 + ((size_t)b * 4096 + n) * 256;
#pragma unroll
      for (int of = 0; of < 4; ++of) {
        int c0 = (ofb + of) * 16 + lk * 4;
        float4 bs = *reinterpret_cast<const float4*>(bb + c0);
        u32 v = pk4(acc[rs][of][0] + bs.x, acc[rs][of][1] + bs.y,
                    acc[rs][of][2] + bs.z, acc[rs][of][3] + bs.w);
        *reinterpret_cast<u32*>(out + c0) = v;
      }
    }
  }
  // ---- mode 2: V (normal) + BN -> [b][n>>5][c][n&31] ----
  {
#pragma unroll
    for (int rs = 0; rs < 2; ++rs)
#pragma unroll
      for (int i = 0; i < 4; ++i) acc[rs][i] = zero;
#pragma unroll
    for (int kk = 0; kk < 8; ++kk)
#pragma unroll
      for (int of = 0; of < 4; ++of) {
        bf16x8 bfv = *reinterpret_cast<const bf16x8*>(
            W16 + 131072 + (size_t)((ofb + of) * 16 + li) * 256 + kk * 32 + lk * 8);
        acc[0][of] = MFMA16(af[0][kk], bfv, acc[0][of], 0, 0, 0);
        acc[1][of] = MFMA16(af[1][kk], bfv, acc[1][of], 0, 0, 0);
      }
#pragma unroll
    for (int of = 0; of < 4; ++of) {
      int c = (ofb + of) * 16 + li;
      float g = rsqrtf(rvar[c] + 1e-5f) * gamma[c];
      float sh = (bm[c] - rmean[c]) * g + beta[c];
#pragma unroll
      for (int rs = 0; rs < 2; ++rs) {
        const int nn0 = n0 + rs * 16 + lk * 4;
        u32 v = pk4(acc[rs][of][0] * g + sh, acc[rs][of][1] * g + sh,
                    acc[rs][of][2] * g + sh, acc[rs][of][3] * g + sh);
        *reinterpret_cast<u32*>(
            V8 + ((size_t)b * 128 + (nn0 >> 5)) * 8192 + c * 32 + (nn0 & 31)) = v;
      }
    }
  }
}

// ---------------------------------------------------------------------------
// Kernel 2: fp8 flash attention, MX K=64 MFMA. Grid = 32qt x KSPLIT x 4b.
//   Single-buffered K/V (32 KB LDS), launch_bounds(256,2) (VGPR ~120 <= 128
//   occupancy step). KSPLIT=8 -> grid 1024 -> 4 blocks/CU, 16 waves/CU.
//   Body identical to r12 (measured spill-free).
// ---------------------------------------------------------------------------
template <int KSPLIT>
__global__ __launch_bounds__(256, 2) void k_attn(
    const unsigned char* __restrict__ Q8, const unsigned char* __restrict__ K8,
    const unsigned char* __restrict__ V8, unsigned short* __restrict__ part,
    float* __restrict__ mpart, float* __restrict__ lpart) {
  constexpr int NT = 4096 / KSPLIT / 64;      // K-tiles per split
  constexpr int CPX = 16 * KSPLIT;            // blocks per XCD chunk
  constexpr int SSH = (KSPLIT == 8) ? 3 : 2;  // log2(KSPLIT)
  __shared__ __align__(32) unsigned char K_lds[64 * 256];  // [key][c], 32B ^= key&7
  __shared__ __align__(32) unsigned char V_lds[2 * 8192];  // [k32][c][32]
  const int bid = blockIdx.x;
  const int swz = (bid & 7) * CPX + (bid >> 3);  // XCD-contiguous, bijective
  const int qt = swz & 31;
  const int bs = swz >> 5;
  const int b = bs >> SSH, s = bs & (KSPLIT - 1);
  const int tid = threadIdx.x, w = tid >> 6, l = tid & 63;
  const int q = l & 31, hi = l >> 5;
  const int rowq = qt * 128 + w * 32 + q;
  i32x8 qf8[4];
  const unsigned char* qp = Q8 + ((size_t)b * 4096 + rowq) * 256 + hi * 32;
#pragma unroll
  for (int kk = 0; kk < 4; ++kk)
    qf8[kk] = *reinterpret_cast<const i32x8*>(qp + kk * 64);
  f32x16 acc[8];
#pragma unroll
  for (int i = 0; i < 8; ++i)
#pragma unroll
    for (int r = 0; r < 16; ++r) acc[i][r] = 0.f;
  float mr = -3e38f, lr = 0.f;

  const int kbase = s * (4096 / KSPLIT);
  auto stageK = [&](int t) {
#pragma unroll
    for (int g = 0; g < 4; ++g) {
      int row = w * 16 + g * 4 + (l >> 4);
      int c16 = (l & 15) ^ ((row & 7) << 1);
      const unsigned char* src =
          K8 + ((size_t)b * 4096 + kbase + t * 64 + row) * 256 + c16 * 16;
      gload_lds16(src, &K_lds[(w * 16 + g * 4) * 256]);
    }
  };
  auto stageV = [&](int t) {
    const unsigned char* base =
        V8 + ((size_t)b * 128 + (kbase >> 5) + t * 2) * 8192;
#pragma unroll
    for (int g = 0; g < 4; ++g)
      gload_lds16(base + (g * 4 + w) * 1024 + l * 16, &V_lds[(g * 4 + w) * 1024]);
  };

  stageK(0);
  stageV(0);
  asm volatile("s_waitcnt vmcnt(0)" ::: "memory");
  __syncthreads();
  for (int t = 0; t < NT; ++t) {
    // ---- QK^T (swapped): S[key][q] ----
    f32x16 S0, S1;
#pragma unroll
    for (int r = 0; r < 16; ++r) { S0[r] = 0.f; S1[r] = 0.f; }
    __builtin_amdgcn_s_setprio(1);
#pragma unroll
    for (int kk = 0; kk < 4; ++kk) {
      int off = (((kk * 2 + hi) ^ (q & 7)) << 5);
      i32x8 kf0 = *reinterpret_cast<const i32x8*>(&K_lds[q * 256 + off]);
      i32x8 kf1 = *reinterpret_cast<const i32x8*>(&K_lds[(32 + q) * 256 + off]);
      S0 = MFMASC(kf0, qf8[kk], S0);
      S1 = MFMASC(kf1, qf8[kk], S1);
    }
    __builtin_amdgcn_s_setprio(0);
    // ---- online softmax (exp2 domain), 4-chain ILP max ----
    float m0 = fmaxf(S0[0], S1[0]), m1 = fmaxf(S0[1], S1[1]);
    float m2 = fmaxf(S0[2], S1[2]), m3 = fmaxf(S0[3], S1[3]);
#pragma unroll
    for (int r = 4; r < 16; r += 4) {
      m0 = fmaxf(m0, fmaxf(S0[r + 0], S1[r + 0]));
      m1 = fmaxf(m1, fmaxf(S0[r + 1], S1[r + 1]));
      m2 = fmaxf(m2, fmaxf(S0[r + 2], S1[r + 2]));
      m3 = fmaxf(m3, fmaxf(S0[r + 3], S1[r + 3]));
    }
    float pmax = fmaxf(fmaxf(m0, m1), fmaxf(m2, m3));
    pmax = fmaxf(pmax, __shfl_xor(pmax, 32));
    if (!__all(pmax - mr <= 7.0f)) {  // defer-max: p <= 2^7 = 128 < 448
      float nm = fmaxf(mr, pmax);
      float sc = exp2f(mr - nm);
      mr = nm;
      lr *= sc;
#pragma unroll
      for (int cb = 0; cb < 8; ++cb)
#pragma unroll
        for (int r = 0; r < 16; ++r) acc[cb][r] *= sc;
    }
#pragma unroll
    for (int r = 0; r < 16; ++r) { S0[r] = exp2f(S0[r] - mr); S1[r] = exp2f(S1[r] - mr); }
    float s0_ = S0[0] + S1[0], s1_ = S0[1] + S1[1];
    float s2_ = S0[2] + S1[2], s3_ = S0[3] + S1[3];
#pragma unroll
    for (int r = 4; r < 16; r += 4) {
      s0_ += S0[r + 0] + S1[r + 0];
      s1_ += S0[r + 1] + S1[r + 1];
      s2_ += S0[r + 2] + S1[r + 2];
      s3_ += S0[r + 3] + S1[r + 3];
    }
    float sum = (s0_ + s1_) + (s2_ + s3_);
    sum += __shfl_xor(sum, 32);
    lr += sum;
    // ---- P -> fp8 B-frag (cvt_pk + permlane32_swap) ----
    u32 A0 = pk4(S0[0], S0[1], S0[2], S0[3]);
    u32 A1 = pk4(S0[4], S0[5], S0[6], S0[7]);
    u32 A2 = pk4(S0[8], S0[9], S0[10], S0[11]);
    u32 A3 = pk4(S0[12], S0[13], S0[14], S0[15]);
    u32 B0 = pk4(S1[0], S1[1], S1[2], S1[3]);
    u32 B1 = pk4(S1[4], S1[5], S1[6], S1[7]);
    u32 B2 = pk4(S1[8], S1[9], S1[10], S1[11]);
    u32 B3 = pk4(S1[12], S1[13], S1[14], S1[15]);
    asm volatile("v_permlane32_swap_b32 %0, %1" : "+v"(A0), "+v"(B0));
    asm volatile("v_permlane32_swap_b32 %0, %1" : "+v"(A1), "+v"(B1));
    asm volatile("v_permlane32_swap_b32 %0, %1" : "+v"(A2), "+v"(B2));
    asm volatile("v_permlane32_swap_b32 %0, %1" : "+v"(A3), "+v"(B3));
    i32x8 pb = (i32x8){(int)A0, (int)B0, (int)A1, (int)B1,
                       (int)A2, (int)B2, (int)A3, (int)B3};
    // ---- PV as O^T ----
    __builtin_amdgcn_s_setprio(1);
#pragma unroll
    for (int cb = 0; cb < 8; ++cb) {
      i32x8 vf = *reinterpret_cast<const i32x8*>(
          &V_lds[hi * 8192 + (cb * 32 + q) * 32]);
      acc[cb] = MFMASC(vf, pb, acc[cb]);
    }
    __builtin_amdgcn_s_setprio(0);
    // ---- restage single buffers ----
    if (t + 1 < NT) {
      __syncthreads();
      stageK(t + 1);
      stageV(t + 1);
      asm volatile("s_waitcnt vmcnt(0)" ::: "memory");
      __syncthreads();
    }
  }
  // ---- store partial: c = cb*32 + (r&3) + 8*(r>>2) + 4*hi ----
  const int sb = s * 4 + b;
  size_t pbase = ((size_t)sb * 4096 + rowq) * 256;
#pragma unroll
  for (int cb = 0; cb < 8; ++cb)
#pragma unroll
    for (int g = 0; g < 4; ++g) {
      ushort4 o;
      o.x = f2b(acc[cb][g * 4 + 0]); o.y = f2b(acc[cb][g * 4 + 1]);
      o.z = f2b(acc[cb][g * 4 + 2]); o.w = f2b(acc[cb][g * 4 + 3]);
      *reinterpret_cast<ushort4*>(&part[pbase + cb * 32 + g * 8 + hi * 4]) = o;
    }
  if (hi == 0) {
    mpart[sb * 4096 + rowq] = mr;
    lpart[sb * 4096 + rowq] = lr;
  }
}

// ---------------------------------------------------------------------------
// Kernel 3: combine NS splits (exp2 domain) + residual epilogue.
//   32 n-rows/block, grid (128,4) = 512 blocks (2/CU).
// ---------------------------------------------------------------------------
template <int NS>
__global__ __launch_bounds__(256) void k_comb(
    const unsigned short* __restrict__ part, const float* __restrict__ mpart,
    const float* __restrict__ lpart, const float* __restrict__ feat,
    const float* __restrict__ alpha, float* __restrict__ out) {
  __shared__ float wgt[NS][32];
  __shared__ float tile[32][261];
  const int nt = blockIdx.x, b = blockIdx.y;
  const int n0 = nt * 32;
  const int tid = threadIdx.x;
  if (tid < 32) {
    int qn = n0 + tid;
    float m[NS], lv[NS];
#pragma unroll
    for (int s = 0; s < NS; ++s) {
      m[s] = mpart[(s * 4 + b) * 4096 + qn];
      lv[s] = lpart[(s * 4 + b) * 4096 + qn];
    }
    float M = m[0];
#pragma unroll
    for (int s = 1; s < NS; ++s) M = fmaxf(M, m[s]);
    float e[NS], L = 0.f;
#pragma unroll
    for (int s = 0; s < NS; ++s) { e[s] = exp2f(m[s] - M); L += e[s] * lv[s]; }
    float inv = 1.0f / L;
#pragma unroll
    for (int s = 0; s < NS; ++s) wgt[s][tid] = e[s] * inv;
  }
  __syncthreads();
  const int row = tid >> 3;            // 32 rows, 8 threads/row
  const int c0 = (tid & 7) * 32;       // 32 channels/thread
  float acc[32];
#pragma unroll
  for (int k = 0; k < 32; ++k) acc[k] = 0.f;
#pragma unroll
  for (int s = 0; s < NS; ++s) {
    float ww = wgt[s][row];
    const unsigned short* p = part + (((size_t)(s * 4 + b)) * 4096 + n0 + row) * 256 + c0;
#pragma unroll
    for (int ch = 0; ch < 4; ++ch) {
      bf16x8 v = *reinterpret_cast<const bf16x8*>(p + ch * 8);
#pragma unroll
      for (int j = 0; j < 8; ++j) acc[ch * 8 + j] += ww * (float)v[j];
    }
  }
#pragma unroll
  for (int k = 0; k < 32; ++k) tile[row][c0 + k] = acc[k];
  __syncthreads();
  const float av = alpha[0];
  const int j = tid & 7, cb = tid >> 3;
#pragma unroll
  for (int p = 0; p < 8; ++p) {
    int c = cb * 8 + p;
    size_t gbase = ((size_t)(b * 256 + c)) * 4096 + n0 + j * 4;
    float4 f4 = *reinterpret_cast<const float4*>(feat + gbase);
    float4 o;
    o.x = f4.x + av * tile[j * 4 + 0][c];
    o.y = f4.y + av * tile[j * 4 + 1][c];
    o.z = f4.z + av * tile[j * 4 + 2][c];
    o.w = f4.w + av * tile[j * 4 + 3][c];
    *reinterpret_cast<float4*>(out + gbase) = o;
  }
}

extern "C" void kernel_launch(void* const* d_in, const int* in_sizes, int n_in,
                              void* d_out, int out_size, void* d_ws, size_t ws_size,
                              hipStream_t stream) {
  const float* feat  = (const float*)d_in[0];
  const float* Wa    = (const float*)d_in[1];
  const float* ba    = (const float*)d_in[2];
  const float* Wb    = (const float*)d_in[3];
  const float* bb    = (const float*)d_in[4];
  const float* Wm    = (const float*)d_in[5];
  const float* bm    = (const float*)d_in[6];
  const float* gamma = (const float*)d_in[7];
  const float* beta  = (const float*)d_in[8];
  const float* rmean = (const float*)d_in[9];
  const float* rvar  = (const float*)d_in[10];
  const float* alpha = (const float*)d_in[11];
  float* out = (float*)d_out;
  char* ws = (char*)d_ws;
  unsigned char* Q8 = (unsigned char*)(ws);                      // [0,4M) fp8 (*log2e)
  unsigned char* K8 = (unsigned char*)(ws + ((size_t)4 << 20));  // [4M,8M) fp8
  unsigned char* V8 = (unsigned char*)(ws + ((size_t)8 << 20));  // [8M,12M) fp8 blocked
  unsigned short* part = (unsigned short*)(ws + ((size_t)12 << 20));
  const bool big = ws_size >= ((size_t)82 << 20);
  // KSPLIT=8 layout: part [12M,76M); W16 at 80M. KSPLIT=4: part [12M,44M); W16 at 44M.
  unsigned short* W16 = (unsigned short*)(ws + (big ? ((size_t)80 << 20) : ((size_t)44 << 20)));
  float* mpart = (float*)((char*)W16 + 524288);
  float* lpart = (float*)((char*)W16 + 524288 + 524288);

  k_wconv<<<dim3(32, 3), 256, 0, stream>>>(Wa, Wb, Wm, W16);
  k_proj<<<dim3(128, 4), 256, 0, stream>>>(feat, W16, ba, bb, bm, gamma, beta,
                                           rmean, rvar, Q8, K8, V8);
  if (big) {
    k_attn<8><<<dim3(1024), 256, 0, stream>>>(Q8, K8, V8, part, mpart, lpart);
    k_comb<8><<<dim3(128, 4), 256, 0, stream>>>(part, mpart, lpart, feat, alpha, out);
  } else {
    k_attn<4><<<dim3(512), 256, 0, stream>>>(Q8, K8, V8, part, mpart, lpart);
    k_comb<4><<<dim3(128, 4), 256, 0, stream>>>(part, mpart, lpart, feat, alpha, out);
  }
}

// Round 14
// 114.548 us; speedup vs baseline: 1.2089x; 1.2089x over previous
//
#include <hip/hip_runtime.h>
#include <hip/hip_bf16.h>

typedef __bf16 bf16x8 __attribute__((ext_vector_type(8)));
typedef float f32x4 __attribute__((ext_vector_type(4)));
typedef float f32x16 __attribute__((ext_vector_type(16)));
typedef int i32x4 __attribute__((ext_vector_type(4)));
typedef int i32x8 __attribute__((ext_vector_type(8)));
typedef unsigned int u32;

#define MFMA16 __builtin_amdgcn_mfma_f32_16x16x32_bf16
// MX-scaled fp8 MFMA, K=64, unity scales (E8M0 byte 0x7F = 2^0)
#define MFMASC(a, b, c) \
  __builtin_amdgcn_mfma_scale_f32_32x32x64_f8f6f4((a), (b), (c), 0, 0, 0, 0x7F7F7F7F, 0, 0x7F7F7F7F)

#define LOG2E 1.44269504f

__device__ __forceinline__ unsigned short f2b(float f) {
  return __builtin_bit_cast(unsigned short, (__bf16)f);
}

__device__ __forceinline__ u32 pk4(float a, float b, float c, float d) {
  int v = __builtin_amdgcn_cvt_pk_fp8_f32(a, b, 0, false);
  v = __builtin_amdgcn_cvt_pk_fp8_f32(c, d, v, true);
  return (u32)v;
}

__device__ __forceinline__ void gload_lds16(const void* g, void* l) {
  __builtin_amdgcn_global_load_lds(
      (const __attribute__((address_space(1))) unsigned int*)g,
      (__attribute__((address_space(3))) unsigned int*)l, 16, 0, 0);
}

// ---------------------------------------------------------------------------
// Kernel 0: W (fp32) -> bf16
// ---------------------------------------------------------------------------
__global__ __launch_bounds__(256) void k_wconv(const float* __restrict__ Wa,
                                               const float* __restrict__ Wb,
                                               const float* __restrict__ Wm,
                                               unsigned short* __restrict__ W16) {
  const int m = blockIdx.y;
  const float* W = (m == 0) ? Wa : (m == 1) ? Wb : Wm;
  const int i = (blockIdx.x * 256 + threadIdx.x) * 8;
  float4 a = *reinterpret_cast<const float4*>(W + i);
  float4 b = *reinterpret_cast<const float4*>(W + i + 4);
  ushort4 lo, hi;
  lo.x = f2b(a.x); lo.y = f2b(a.y); lo.z = f2b(a.z); lo.w = f2b(a.w);
  hi.x = f2b(b.x); hi.y = f2b(b.y); hi.z = f2b(b.z); hi.w = f2b(b.w);
  unsigned short* dst = W16 + m * 65536 + i;
  *reinterpret_cast<ushort4*>(dst) = lo;
  *reinterpret_cast<ushort4*>(dst + 4) = hi;
}

// ---------------------------------------------------------------------------
// Kernel 1: fused transpose + 3 projections. 32 n-rows/block, grid (128,4).
// ---------------------------------------------------------------------------
__global__ __launch_bounds__(256) void k_proj(
    const float* __restrict__ x, const unsigned short* __restrict__ W16,
    const float* __restrict__ ba, const float* __restrict__ bb,
    const float* __restrict__ bm, const float* __restrict__ gamma,
    const float* __restrict__ beta, const float* __restrict__ rmean,
    const float* __restrict__ rvar,
    unsigned char* __restrict__ Q8, unsigned char* __restrict__ K8,
    unsigned char* __restrict__ V8) {
  __shared__ float tile[256][36];
  __shared__ __align__(16) unsigned short XT_lds[32 * 256];
  const int nt = blockIdx.x, b = blockIdx.y;
  const int n0 = nt * 32;
  const int tid = threadIdx.x, w = tid >> 6, l = tid & 63;
  const int li = l & 15, lk = l >> 4;
  {
    const int cr = tid >> 3, j4 = (tid & 7) * 4;
#pragma unroll
    for (int p = 0; p < 8; ++p) {
      int c = p * 32 + cr;
      float4 v = *reinterpret_cast<const float4*>(
          x + ((size_t)(b * 256 + c)) * 4096 + n0 + j4);
      *reinterpret_cast<float4*>(&tile[c][j4]) = v;
    }
  }
  __syncthreads();
  {
    const int n = tid & 31, cb8 = (tid >> 5) * 32;
#pragma unroll
    for (int p = 0; p < 8; ++p) {
      int c0 = cb8 + p * 4;
      ushort4 o;
      o.x = f2b(tile[c0][n]); o.y = f2b(tile[c0 + 1][n]);
      o.z = f2b(tile[c0 + 2][n]); o.w = f2b(tile[c0 + 3][n]);
      unsigned off = ((unsigned)(n * 512 + c0 * 2)) ^ (unsigned)((n & 7) << 4);
      *reinterpret_cast<ushort4*>((char*)XT_lds + off) = o;
    }
  }
  __syncthreads();
  bf16x8 af[2][8];
#pragma unroll
  for (int rs = 0; rs < 2; ++rs) {
    const int row = rs * 16 + li;
#pragma unroll
    for (int kk = 0; kk < 8; ++kk) {
      unsigned off = ((unsigned)(row * 512 + kk * 64 + lk * 16)) ^ (unsigned)((row & 7) << 4);
      af[rs][kk] = *reinterpret_cast<const bf16x8*>((const char*)XT_lds + off);
    }
  }
  const int ofb = w * 4;
  f32x4 zero = {0.f, 0.f, 0.f, 0.f};
  f32x4 acc[2][4];
  // ---- mode 0: Q (swapped), *log2e ----
  {
#pragma unroll
    for (int rs = 0; rs < 2; ++rs)
#pragma unroll
      for (int i = 0; i < 4; ++i) acc[rs][i] = zero;
#pragma unroll
    for (int kk = 0; kk < 8; ++kk)
#pragma unroll
      for (int of = 0; of < 4; ++of) {
        bf16x8 bfv = *reinterpret_cast<const bf16x8*>(
            W16 + (size_t)((ofb + of) * 16 + li) * 256 + kk * 32 + lk * 8);
        acc[0][of] = MFMA16(bfv, af[0][kk], acc[0][of], 0, 0, 0);
        acc[1][of] = MFMA16(bfv, af[1][kk], acc[1][of], 0, 0, 0);
      }
#pragma unroll
    for (int rs = 0; rs < 2; ++rs) {
      const int n = n0 + rs * 16 + li;
      unsigned char* out = Q8 + ((size_t)b * 4096 + n) * 256;
#pragma unroll
      for (int of = 0; of < 4; ++of) {
        int c0 = (ofb + of) * 16 + lk * 4;
        float4 bs = *reinterpret_cast<const float4*>(ba + c0);
        u32 v = pk4((acc[rs][of][0] + bs.x) * LOG2E, (acc[rs][of][1] + bs.y) * LOG2E,
                    (acc[rs][of][2] + bs.z) * LOG2E, (acc[rs][of][3] + bs.w) * LOG2E);
        *reinterpret_cast<u32*>(out + c0) = v;
      }
    }
  }
  // ---- mode 1: K (swapped) ----
  {
#pragma unroll
    for (int rs = 0; rs < 2; ++rs)
#pragma unroll
      for (int i = 0; i < 4; ++i) acc[rs][i] = zero;
#pragma unroll
    for (int kk = 0; kk < 8; ++kk)
#pragma unroll
      for (int of = 0; of < 4; ++of) {
        bf16x8 bfv = *reinterpret_cast<const bf16x8*>(
            W16 + 65536 + (size_t)((ofb + of) * 16 + li) * 256 + kk * 32 + lk * 8);
        acc[0][of] = MFMA16(bfv, af[0][kk], acc[0][of], 0, 0, 0);
        acc[1][of] = MFMA16(bfv, af[1][kk], acc[1][of], 0, 0, 0);
      }
#pragma unroll
    for (int rs = 0; rs < 2; ++rs) {
      const int n = n0 + rs * 16 + li;
      unsigned char* out = K8 + ((size_t)b * 4096 + n) * 256;
#pragma unroll
      for (int of = 0; of < 4; ++of) {
        int c0 = (ofb + of) * 16 + lk * 4;
        float4 bs = *reinterpret_cast<const float4*>(bb + c0);
        u32 v = pk4(acc[rs][of][0] + bs.x, acc[rs][of][1] + bs.y,
                    acc[rs][of][2] + bs.z, acc[rs][of][3] + bs.w);
        *reinterpret_cast<u32*>(out + c0) = v;
      }
    }
  }
  // ---- mode 2: V (normal) + BN -> [b][n>>5][c][n&31] ----
  {
#pragma unroll
    for (int rs = 0; rs < 2; ++rs)
#pragma unroll
      for (int i = 0; i < 4; ++i) acc[rs][i] = zero;
#pragma unroll
    for (int kk = 0; kk < 8; ++kk)
#pragma unroll
      for (int of = 0; of < 4; ++of) {
        bf16x8 bfv = *reinterpret_cast<const bf16x8*>(
            W16 + 131072 + (size_t)((ofb + of) * 16 + li) * 256 + kk * 32 + lk * 8);
        acc[0][of] = MFMA16(af[0][kk], bfv, acc[0][of], 0, 0, 0);
        acc[1][of] = MFMA16(af[1][kk], bfv, acc[1][of], 0, 0, 0);
      }
#pragma unroll
    for (int of = 0; of < 4; ++of) {
      int c = (ofb + of) * 16 + li;
      float g = rsqrtf(rvar[c] + 1e-5f) * gamma[c];
      float sh = (bm[c] - rmean[c]) * g + beta[c];
#pragma unroll
      for (int rs = 0; rs < 2; ++rs) {
        const int nn0 = n0 + rs * 16 + lk * 4;
        u32 v = pk4(acc[rs][of][0] * g + sh, acc[rs][of][1] * g + sh,
                    acc[rs][of][2] * g + sh, acc[rs][of][3] * g + sh);
        *reinterpret_cast<u32*>(
            V8 + ((size_t)b * 128 + (nn0 >> 5)) * 8192 + c * 32 + (nn0 & 31)) = v;
      }
    }
  }
}

// ---------------------------------------------------------------------------
// Kernel 2: fp8 flash attention, MX K=64 MFMA. Grid 512 = 32qt x 4s x 4b.
//   r12 body + V double-buffered (48 KB LDS) with stage issue moved to just
//   after the post-QK barrier: K restage + next-V land under softmax+PV, so
//   the end-of-tile vmcnt(0) is ~free. max3 tree for the row-max reduce.
//   Unified-file budget: 120 VGPR + 128 acc = 248 <= 256 (2 waves/SIMD cap).
// ---------------------------------------------------------------------------
__global__ __launch_bounds__(256, 2) void k_attn(
    const unsigned char* __restrict__ Q8, const unsigned char* __restrict__ K8,
    const unsigned char* __restrict__ V8, unsigned short* __restrict__ part,
    float* __restrict__ mpart, float* __restrict__ lpart) {
  __shared__ __align__(32) unsigned char K_lds[64 * 256];     // [key][c], 32B ^= key&7
  __shared__ __align__(32) unsigned char V_lds[2][2 * 8192];  // dbuf [k32][c][32]
  const int bid = blockIdx.x;
  const int swz = (bid & 7) * 64 + (bid >> 3);
  const int qt = swz & 31;
  const int bs = swz >> 5;
  const int b = bs >> 2, s = bs & 3;
  const int tid = threadIdx.x, w = tid >> 6, l = tid & 63;
  const int q = l & 31, hi = l >> 5;
  const int rowq = qt * 128 + w * 32 + q;
  i32x8 qf8[4];
  const unsigned char* qp = Q8 + ((size_t)b * 4096 + rowq) * 256 + hi * 32;
#pragma unroll
  for (int kk = 0; kk < 4; ++kk)
    qf8[kk] = *reinterpret_cast<const i32x8*>(qp + kk * 64);
  f32x16 acc[8];
#pragma unroll
  for (int i = 0; i < 8; ++i)
#pragma unroll
    for (int r = 0; r < 16; ++r) acc[i][r] = 0.f;
  float mr = -3e38f, lr = 0.f;

  const int kbase = s * 1024;
  auto stageK = [&](int t) {
#pragma unroll
    for (int g = 0; g < 4; ++g) {
      int row = w * 16 + g * 4 + (l >> 4);
      int c16 = (l & 15) ^ ((row & 7) << 1);
      const unsigned char* src =
          K8 + ((size_t)b * 4096 + kbase + t * 64 + row) * 256 + c16 * 16;
      gload_lds16(src, &K_lds[(w * 16 + g * 4) * 256]);
    }
  };
  auto stageV = [&](int buf, int t) {
    const unsigned char* base =
        V8 + ((size_t)b * 128 + (kbase >> 5) + t * 2) * 8192;
#pragma unroll
    for (int g = 0; g < 4; ++g)
      gload_lds16(base + (g * 4 + w) * 1024 + l * 16, &V_lds[buf][(g * 4 + w) * 1024]);
  };

  stageK(0);
  stageV(0, 0);
  asm volatile("s_waitcnt vmcnt(0)" ::: "memory");
  __syncthreads();
  int cur = 0;
  for (int t = 0; t < 16; ++t) {
    // ---- QK^T (swapped): S[key][q], reads K_lds ----
    f32x16 S0, S1;
#pragma unroll
    for (int r = 0; r < 16; ++r) { S0[r] = 0.f; S1[r] = 0.f; }
    __builtin_amdgcn_s_setprio(1);
#pragma unroll
    for (int kk = 0; kk < 4; ++kk) {
      int off = (((kk * 2 + hi) ^ (q & 7)) << 5);
      i32x8 kf0 = *reinterpret_cast<const i32x8*>(&K_lds[q * 256 + off]);
      i32x8 kf1 = *reinterpret_cast<const i32x8*>(&K_lds[(32 + q) * 256 + off]);
      S0 = MFMASC(kf0, qf8[kk], S0);
      S1 = MFMASC(kf1, qf8[kk], S1);
    }
    __builtin_amdgcn_s_setprio(0);
    // ---- early restage: K reads done after barrier; V goes to other buf.
    //      Loads land during softmax+PV (~700 cyc) -> end-of-tile wait ~free.
    if (t + 1 < 16) {
      __syncthreads();
      stageK(t + 1);
      stageV(cur ^ 1, t + 1);
    }
    // ---- online softmax (exp2 domain), max3 reduce tree ----
    float m0 = fmaxf(fmaxf(S0[0], S1[0]), S0[4]);
    m0 = fmaxf(fmaxf(m0, S1[4]), S0[8]);
    m0 = fmaxf(fmaxf(m0, S1[8]), S0[12]);
    m0 = fmaxf(m0, S1[12]);
    float m1 = fmaxf(fmaxf(S0[1], S1[1]), S0[5]);
    m1 = fmaxf(fmaxf(m1, S1[5]), S0[9]);
    m1 = fmaxf(fmaxf(m1, S1[9]), S0[13]);
    m1 = fmaxf(m1, S1[13]);
    float m2 = fmaxf(fmaxf(S0[2], S1[2]), S0[6]);
    m2 = fmaxf(fmaxf(m2, S1[6]), S0[10]);
    m2 = fmaxf(fmaxf(m2, S1[10]), S0[14]);
    m2 = fmaxf(m2, S1[14]);
    float m3 = fmaxf(fmaxf(S0[3], S1[3]), S0[7]);
    m3 = fmaxf(fmaxf(m3, S1[7]), S0[11]);
    m3 = fmaxf(fmaxf(m3, S1[11]), S0[15]);
    m3 = fmaxf(m3, S1[15]);
    float pmax = fmaxf(fmaxf(fmaxf(m0, m1), m2), m3);
    pmax = fmaxf(pmax, __shfl_xor(pmax, 32));
    if (!__all(pmax - mr <= 7.0f)) {  // defer-max: p <= 2^7 = 128 < 448
      float nm = fmaxf(mr, pmax);
      float sc = exp2f(mr - nm);
      mr = nm;
      lr *= sc;
#pragma unroll
      for (int cb = 0; cb < 8; ++cb)
#pragma unroll
        for (int r = 0; r < 16; ++r) acc[cb][r] *= sc;
    }
#pragma unroll
    for (int r = 0; r < 16; ++r) { S0[r] = exp2f(S0[r] - mr); S1[r] = exp2f(S1[r] - mr); }
    float s0_ = S0[0] + S1[0], s1_ = S0[1] + S1[1];
    float s2_ = S0[2] + S1[2], s3_ = S0[3] + S1[3];
#pragma unroll
    for (int r = 4; r < 16; r += 4) {
      s0_ += S0[r + 0] + S1[r + 0];
      s1_ += S0[r + 1] + S1[r + 1];
      s2_ += S0[r + 2] + S1[r + 2];
      s3_ += S0[r + 3] + S1[r + 3];
    }
    float sum = (s0_ + s1_) + (s2_ + s3_);
    sum += __shfl_xor(sum, 32);
    lr += sum;
    // ---- P -> fp8 B-frag (cvt_pk + permlane32_swap) ----
    u32 A0 = pk4(S0[0], S0[1], S0[2], S0[3]);
    u32 A1 = pk4(S0[4], S0[5], S0[6], S0[7]);
    u32 A2 = pk4(S0[8], S0[9], S0[10], S0[11]);
    u32 A3 = pk4(S0[12], S0[13], S0[14], S0[15]);
    u32 B0 = pk4(S1[0], S1[1], S1[2], S1[3]);
    u32 B1 = pk4(S1[4], S1[5], S1[6], S1[7]);
    u32 B2 = pk4(S1[8], S1[9], S1[10], S1[11]);
    u32 B3 = pk4(S1[12], S1[13], S1[14], S1[15]);
    asm volatile("v_permlane32_swap_b32 %0, %1" : "+v"(A0), "+v"(B0));
    asm volatile("v_permlane32_swap_b32 %0, %1" : "+v"(A1), "+v"(B1));
    asm volatile("v_permlane32_swap_b32 %0, %1" : "+v"(A2), "+v"(B2));
    asm volatile("v_permlane32_swap_b32 %0, %1" : "+v"(A3), "+v"(B3));
    i32x8 pb = (i32x8){(int)A0, (int)B0, (int)A1, (int)B1,
                       (int)A2, (int)B2, (int)A3, (int)B3};
    // ---- PV as O^T: reads V_lds[cur] ----
    __builtin_amdgcn_s_setprio(1);
#pragma unroll
    for (int cb = 0; cb < 8; ++cb) {
      i32x8 vf = *reinterpret_cast<const i32x8*>(
          &V_lds[cur][hi * 8192 + (cb * 32 + q) * 32]);
      acc[cb] = MFMASC(vf, pb, acc[cb]);
    }
    __builtin_amdgcn_s_setprio(0);
    if (t + 1 < 16) {
      asm volatile("s_waitcnt vmcnt(0)" ::: "memory");
      __syncthreads();
      cur ^= 1;
    }
  }
  // ---- store partial: c = cb*32 + (r&3) + 8*(r>>2) + 4*hi ----
  const int sb = s * 4 + b;
  size_t pbase = ((size_t)sb * 4096 + rowq) * 256;
#pragma unroll
  for (int cb = 0; cb < 8; ++cb)
#pragma unroll
    for (int g = 0; g < 4; ++g) {
      ushort4 o;
      o.x = f2b(acc[cb][g * 4 + 0]); o.y = f2b(acc[cb][g * 4 + 1]);
      o.z = f2b(acc[cb][g * 4 + 2]); o.w = f2b(acc[cb][g * 4 + 3]);
      *reinterpret_cast<ushort4*>(&part[pbase + cb * 32 + g * 8 + hi * 4]) = o;
    }
  if (hi == 0) {
    mpart[sb * 4096 + rowq] = mr;
    lpart[sb * 4096 + rowq] = lr;
  }
}

// ---------------------------------------------------------------------------
// Kernel 3: combine 4 splits (exp2 domain) + residual epilogue.
//   32 n-rows/block, grid (128,4) = 512 blocks (2/CU).
// ---------------------------------------------------------------------------
__global__ __launch_bounds__(256) void k_comb(
    const unsigned short* __restrict__ part, const float* __restrict__ mpart,
    const float* __restrict__ lpart, const float* __restrict__ feat,
    const float* __restrict__ alpha, float* __restrict__ out) {
  __shared__ float wgt[4][32];
  __shared__ float tile[32][261];
  const int nt = blockIdx.x, b = blockIdx.y;
  const int n0 = nt * 32;
  const int tid = threadIdx.x;
  if (tid < 32) {
    int qn = n0 + tid;
    float m[4], lv[4];
#pragma unroll
    for (int s = 0; s < 4; ++s) {
      m[s] = mpart[(s * 4 + b) * 4096 + qn];
      lv[s] = lpart[(s * 4 + b) * 4096 + qn];
    }
    float M = fmaxf(fmaxf(m[0], m[1]), fmaxf(m[2], m[3]));
    float e[4], L = 0.f;
#pragma unroll
    for (int s = 0; s < 4; ++s) { e[s] = exp2f(m[s] - M); L += e[s] * lv[s]; }
    float inv = 1.0f / L;
#pragma unroll
    for (int s = 0; s < 4; ++s) wgt[s][tid] = e[s] * inv;
  }
  __syncthreads();
  const int row = tid >> 3;            // 32 rows, 8 threads/row
  const int c0 = (tid & 7) * 32;       // 32 channels/thread
  float acc[32];
#pragma unroll
  for (int k = 0; k < 32; ++k) acc[k] = 0.f;
#pragma unroll
  for (int s = 0; s < 4; ++s) {
    float ww = wgt[s][row];
    const unsigned short* p = part + (((size_t)(s * 4 + b)) * 4096 + n0 + row) * 256 + c0;
#pragma unroll
    for (int ch = 0; ch < 4; ++ch) {
      bf16x8 v = *reinterpret_cast<const bf16x8*>(p + ch * 8);
#pragma unroll
      for (int j = 0; j < 8; ++j) acc[ch * 8 + j] += ww * (float)v[j];
    }
  }
#pragma unroll
  for (int k = 0; k < 32; ++k) tile[row][c0 + k] = acc[k];
  __syncthreads();
  const float av = alpha[0];
  const int j = tid & 7, cb = tid >> 3;
#pragma unroll
  for (int p = 0; p < 8; ++p) {
    int c = cb * 8 + p;
    size_t gbase = ((size_t)(b * 256 + c)) * 4096 + n0 + j * 4;
    float4 f4 = *reinterpret_cast<const float4*>(feat + gbase);
    float4 o;
    o.x = f4.x + av * tile[j * 4 + 0][c];
    o.y = f4.y + av * tile[j * 4 + 1][c];
    o.z = f4.z + av * tile[j * 4 + 2][c];
    o.w = f4.w + av * tile[j * 4 + 3][c];
    *reinterpret_cast<float4*>(out + gbase) = o;
  }
}

extern "C" void kernel_launch(void* const* d_in, const int* in_sizes, int n_in,
                              void* d_out, int out_size, void* d_ws, size_t ws_size,
                              hipStream_t stream) {
  const float* feat  = (const float*)d_in[0];
  const float* Wa    = (const float*)d_in[1];
  const float* ba    = (const float*)d_in[2];
  const float* Wb    = (const float*)d_in[3];
  const float* bb    = (const float*)d_in[4];
  const float* Wm    = (const float*)d_in[5];
  const float* bm    = (const float*)d_in[6];
  const float* gamma = (const float*)d_in[7];
  const float* beta  = (const float*)d_in[8];
  const float* rmean = (const float*)d_in[9];
  const float* rvar  = (const float*)d_in[10];
  const float* alpha = (const float*)d_in[11];
  float* out = (float*)d_out;
  char* ws = (char*)d_ws;
  unsigned char*  Q8   = (unsigned char*)(ws);                        // [0,4M) fp8 (*log2e)
  unsigned char*  K8   = (unsigned char*)(ws + ((size_t)4 << 20));    // [4M,8M) fp8
  unsigned char*  V8   = (unsigned char*)(ws + ((size_t)8 << 20));    // [8M,12M) fp8 blocked
  unsigned short* part = (unsigned short*)(ws + ((size_t)16 << 20));  // [16M,48M) bf16
  unsigned short* W16  = (unsigned short*)(ws + ((size_t)48 << 20));  // 384K bf16
  float* mpart = (float*)(ws + ((size_t)48 << 20) + 393216);
  float* lpart = (float*)(ws + ((size_t)48 << 20) + 393216 + 262144);

  k_wconv<<<dim3(32, 3), 256, 0, stream>>>(Wa, Wb, Wm, W16);
  k_proj<<<dim3(128, 4), 256, 0, stream>>>(feat, W16, ba, bb, bm, gamma, beta,
                                           rmean, rvar, Q8, K8, V8);
  k_attn<<<dim3(512), 256, 0, stream>>>(Q8, K8, V8, part, mpart, lpart);
  k_comb<<<dim3(128, 4), 256, 0, stream>>>(part, mpart, lpart, feat, alpha, out);
}